// Round 10
// baseline (314.738 us; speedup 1.0000x reference)
//
#include <hip/hip_runtime.h>
#include <hip/hip_bf16.h>
#include <hip/hip_fp16.h>

#define NEG_SLOPE 0.2f

typedef __attribute__((ext_vector_type(8))) short bf16x8;
typedef __attribute__((ext_vector_type(4))) float f32x4;

__device__ __forceinline__ unsigned pack_bf16(float a, float b) {
    unsigned ua = __float_as_uint(a), ub = __float_as_uint(b);
    ua += 0x7FFFu + ((ua >> 16) & 1u);
    ub += 0x7FFFu + ((ub >> 16) & 1u);
    return (ua >> 16) | (ub & 0xFFFF0000u);
}

__device__ __forceinline__ unsigned pack_f16(float a, float b) {
    union { __half2 h; unsigned u; } cv;
    cv.h = __floats2half2_rn(a, b);
    return cv.u;
}

// ============================================================================
// Fused MFMA kernel: x = relu(embed@W_lin+b_lin); feat = x@W_gat;
// el = feat@attn_l; er = feat@attn_r.
// feat stored STRAIGHT fp16 pairs: feat_u32[n*64+u] = (f16(feat[2u]), f16(feat[2u+1]))
// ============================================================================
__global__ __launch_bounds__(256) void k_gemm(
    const float* __restrict__ embed, const float* __restrict__ W_lin,
    const float* __restrict__ b_lin, const float* __restrict__ W_gat,
    const float* __restrict__ attn_l, const float* __restrict__ attn_r,
    unsigned* __restrict__ feat_u32, float* __restrict__ el,
    float* __restrict__ er, int N)
{
    __shared__ __align__(16) char lds[40960];
    const int t = threadIdx.x;
    const int lane = t & 63;
    const int w = t >> 6;
    const int lc = lane & 15;
    const int hg = lane >> 4;
    const int nb = blockIdx.x * 128;

    // ---- stage W_lin transposed bf16 into LDS [c][k], swizzled ----
    for (int i = t; i < 6144; i += 256) {          // pairs: c in [0,64), kp in [0,96)
        const int c = i & 63, kp = i >> 6;
        const float w0 = W_lin[(2 * kp) * 64 + c];
        const float w1 = W_lin[(2 * kp + 1) * 64 + c];
        const unsigned off = (unsigned)(c * 384 + kp * 4) ^ ((c & 7) << 4);
        *(unsigned*)(lds + off) = pack_bf16(w0, w1);
    }
    // ---- stage W_gat transposed bf16 into LDS [c][k], swizzled ----
    for (int i = t; i < 4096; i += 256) {          // pairs: c in [0,128), kp in [0,32)
        const int c = i & 127, kp = i >> 7;
        const float w0 = W_gat[(2 * kp) * 128 + c];
        const float w1 = W_gat[(2 * kp + 1) * 128 + c];
        const unsigned off = (unsigned)(c * 128 + kp * 4) ^ ((c & 7) << 4);
        *(unsigned*)(lds + 24576 + off) = pack_bf16(w0, w1);
    }
    __syncthreads();

    // ---- GEMM1: x[128][64] = relu(embed[128][192] @ W_lin + b_lin) ----
    f32x4 acc1[2][4];
#pragma unroll
    for (int mt = 0; mt < 2; mt++)
#pragma unroll
        for (int nt = 0; nt < 4; nt++) acc1[mt][nt] = (f32x4)0.f;

#pragma unroll
    for (int ks = 0; ks < 6; ks++) {
        bf16x8 bfr[4];
#pragma unroll
        for (int nt = 0; nt < 4; nt++) {
            const int c = nt * 16 + lc;
            const unsigned off = (unsigned)(c * 384 + ks * 64 + hg * 16) ^ ((c & 7) << 4);
            bfr[nt] = *(const bf16x8*)(lds + off);
        }
#pragma unroll
        for (int mt = 0; mt < 2; mt++) {
            int row = nb + w * 32 + mt * 16 + lc;
            if (row >= N) row = N - 1;
            const float4* ep = (const float4*)(embed + (size_t)row * 192 + ks * 32 + hg * 8);
            const float4 p = ep[0], q = ep[1];
            union { bf16x8 v; unsigned u[4]; } a;
            a.u[0] = pack_bf16(p.x, p.y); a.u[1] = pack_bf16(p.z, p.w);
            a.u[2] = pack_bf16(q.x, q.y); a.u[3] = pack_bf16(q.z, q.w);
#pragma unroll
            for (int nt = 0; nt < 4; nt++)
                acc1[mt][nt] = __builtin_amdgcn_mfma_f32_16x16x32_bf16(a.v, bfr[nt], acc1[mt][nt], 0, 0, 0);
        }
    }

    float blv[4];
#pragma unroll
    for (int nt = 0; nt < 4; nt++) blv[nt] = b_lin[nt * 16 + lc];

    __syncthreads();  // all WT_lin reads done before x overwrites region 0

    // write x (bf16, swizzled) to LDS region 0
#pragma unroll
    for (int mt = 0; mt < 2; mt++)
#pragma unroll
        for (int nt = 0; nt < 4; nt++)
#pragma unroll
            for (int r = 0; r < 4; r++) {
                float v = acc1[mt][nt][r] + blv[nt];
                v = v > 0.f ? v : 0.f;
                const int xrow = w * 32 + mt * 16 + 4 * hg + r;
                const int col = nt * 16 + lc;
                const unsigned off = (unsigned)(xrow * 128 + col * 2) ^ ((xrow & 7) << 4);
                unsigned bv = __float_as_uint(v);
                bv += 0x7FFFu + ((bv >> 16) & 1u);
                *(unsigned short*)(lds + off) = (unsigned short)(bv >> 16);
            }
    __syncthreads();

    // ---- GEMM2: feat[128][128] = x[128][64] @ W_gat ----
    f32x4 acc2[2][8];
#pragma unroll
    for (int mt = 0; mt < 2; mt++)
#pragma unroll
        for (int nt = 0; nt < 8; nt++) acc2[mt][nt] = (f32x4)0.f;

#pragma unroll
    for (int ks = 0; ks < 2; ks++) {
        bf16x8 a2[2];
#pragma unroll
        for (int mt = 0; mt < 2; mt++) {
            const int row = w * 32 + mt * 16 + lc;
            const unsigned off = (unsigned)(row * 128 + ks * 64 + hg * 16) ^ ((row & 7) << 4);
            a2[mt] = *(const bf16x8*)(lds + off);
        }
#pragma unroll
        for (int nt = 0; nt < 8; nt++) {
            const int c = nt * 16 + lc;
            const unsigned off = (unsigned)(c * 128 + ks * 64 + hg * 16) ^ ((c & 7) << 4);
            const bf16x8 b2 = *(const bf16x8*)(lds + 24576 + off);
            acc2[0][nt] = __builtin_amdgcn_mfma_f32_16x16x32_bf16(a2[0], b2, acc2[0][nt], 0, 0, 0);
            acc2[1][nt] = __builtin_amdgcn_mfma_f32_16x16x32_bf16(a2[1], b2, acc2[1][nt], 0, 0, 0);
        }
    }

    // ---- epilogue: el/er + straight-paired feat writes ----
    float alv[8], arv[8];
#pragma unroll
    for (int nt = 0; nt < 8; nt++) {
        alv[nt] = attn_l[nt * 16 + lc];
        arv[nt] = attn_r[nt * 16 + lc];
    }

#pragma unroll
    for (int mt = 0; mt < 2; mt++) {
        const int rbase = nb + w * 32 + mt * 16 + 4 * hg;
        // feat: straight pairs (c, c+1). Lane lc owns col c = nt*16+lc;
        // partner col via shfl_xor(1) (uniform flow); even lanes store u32.
#pragma unroll
        for (int nt = 0; nt < 8; nt++)
#pragma unroll
            for (int r = 0; r < 4; r++) {
                const float V = acc2[mt][nt][r];
                const float Vp = __shfl_xor(V, 1, 64);
                const int row = rbase + r;
                if (!(lc & 1) && row < N)
                    feat_u32[(size_t)row * 64 + nt * 8 + (lc >> 1)] = pack_f16(V, Vp);
            }
        // el/er
        float elv[4] = {0.f, 0.f, 0.f, 0.f}, erv[4] = {0.f, 0.f, 0.f, 0.f};
#pragma unroll
        for (int nt = 0; nt < 8; nt++)
#pragma unroll
            for (int r = 0; r < 4; r++) {
                elv[r] = fmaf(acc2[mt][nt][r], alv[nt], elv[r]);
                erv[r] = fmaf(acc2[mt][nt][r], arv[nt], erv[r]);
            }
#pragma unroll
        for (int r = 0; r < 4; r++) {
#pragma unroll
            for (int o = 1; o < 16; o <<= 1) {
                elv[r] += __shfl_xor(elv[r], o, 64);
                erv[r] += __shfl_xor(erv[r], o, 64);
            }
            const int row = rbase + r;
            if (lc == r && row < N) { el[row] = elv[r]; er[row] = erv[r]; }
        }
    }
}

// histogram + per-edge rank (atomicAdd's return value), ranks stored coalesced
__global__ void k_hist(const int* __restrict__ dst, int* __restrict__ counts,
                       int* __restrict__ rank, int E) {
    const int i = (blockIdx.x * 256 + threadIdx.x) * 4;
    if (i + 3 < E) {
        const int4 v = *(const int4*)&dst[i];
        int4 r;
        r.x = atomicAdd(&counts[v.x], 1);
        r.y = atomicAdd(&counts[v.y], 1);
        r.z = atomicAdd(&counts[v.z], 1);
        r.w = atomicAdd(&counts[v.w], 1);
        *(int4*)&rank[i] = r;
    } else {
        for (int j = i; j < E; j++) rank[j] = atomicAdd(&counts[dst[j]], 1);
    }
}

__global__ __launch_bounds__(256) void k_scan1(
    const int* __restrict__ counts, int* __restrict__ offs,
    int* __restrict__ blocksums, int N)
{
    __shared__ int lds[256];
    const int t = threadIdx.x;
    const int base = blockIdx.x * 1024 + t * 4;
    int c0 = 0, c1 = 0, c2 = 0, c3 = 0;
    if (base + 3 < N) {
        int4 v = *(const int4*)&counts[base];
        c0 = v.x; c1 = v.y; c2 = v.z; c3 = v.w;
    } else {
        if (base + 0 < N) c0 = counts[base + 0];
        if (base + 1 < N) c1 = counts[base + 1];
        if (base + 2 < N) c2 = counts[base + 2];
        if (base + 3 < N) c3 = counts[base + 3];
    }
    const int s = c0 + c1 + c2 + c3;
    lds[t] = s;
    __syncthreads();
    for (int o = 1; o < 256; o <<= 1) {
        int u = (t >= o) ? lds[t - o] : 0;
        __syncthreads();
        lds[t] += u;
        __syncthreads();
    }
    const int excl = lds[t] - s;
    int o0 = excl, o1 = excl + c0, o2 = o1 + c1, o3 = o2 + c2;
    if (base + 3 < N) {
        *(int4*)&offs[base] = make_int4(o0, o1, o2, o3);
    } else {
        if (base + 0 < N) offs[base + 0] = o0;
        if (base + 1 < N) offs[base + 1] = o1;
        if (base + 2 < N) offs[base + 2] = o2;
        if (base + 3 < N) offs[base + 3] = o3;
    }
    if (t == 255) blocksums[blockIdx.x] = lds[255];
}

__global__ void k_scan2(int* __restrict__ blocksums, int nb) {
    __shared__ int lds[128];
    const int t = threadIdx.x;
    const int v = (t < nb) ? blocksums[t] : 0;
    lds[t] = v;
    __syncthreads();
    for (int o = 1; o < 128; o <<= 1) {
        int u = (t >= o) ? lds[t - o] : 0;
        __syncthreads();
        lds[t] += u;
        __syncthreads();
    }
    if (t < nb) blocksums[t] = lds[t] - v;
}

__global__ void k_scan3(int* __restrict__ offs, const int* __restrict__ blocksums,
                        int N, int E) {
    int i = blockIdx.x * 256 + threadIdx.x;
    if (i < N) offs[i] += blocksums[i >> 10];
    if (i == 0) offs[N] = E;  // sentinel
}

// scatter (src | localSeg<<20) into CSR slot: pos = offs[dst] + rank.
// localSeg = dst & 15 (tile-local segment id) -> k_agg needs NO search.
__global__ void k_scat(const int* __restrict__ src, const int* __restrict__ dst,
                       const int* __restrict__ rank, const int* __restrict__ offs,
                       unsigned* __restrict__ csru, int E) {
    const int i = (blockIdx.x * 256 + threadIdx.x) * 4;
    if (i + 3 < E) {
        const int4 s4 = *(const int4*)&src[i];
        const int4 d4 = *(const int4*)&dst[i];
        const int4 r4 = *(const int4*)&rank[i];
        csru[offs[d4.x] + r4.x] = (unsigned)s4.x | ((unsigned)(d4.x & 15) << 20);
        csru[offs[d4.y] + r4.y] = (unsigned)s4.y | ((unsigned)(d4.y & 15) << 20);
        csru[offs[d4.z] + r4.z] = (unsigned)s4.z | ((unsigned)(d4.z & 15) << 20);
        csru[offs[d4.w] + r4.w] = (unsigned)s4.w | ((unsigned)(d4.w & 15) << 20);
    } else {
        for (int j = i; j < E; j++)
            csru[offs[dst[j]] + rank[j]] = (unsigned)src[j] | ((unsigned)(dst[j] & 15) << 20);
    }
}

// ============================================================================
// k_agg v10: v9's proven MFMA-window structure + 2-ahead software pipeline.
// Stage schedule per iteration i (window w):
//   S0(i+2): csru load (2 windows ahead)
//   S3(i):   ds_write gv -> LDS (gathered last iteration; vmcnt by compiler)
//   A-build(i) from p_c/m_c (uniform-flow shfls)
//   S1(i+1): sj/m/p from ev_n (el gather + er direct load, exec-masked)
//   S2(i+1): 8 feat uint4 gathers -> gv regs (regs = 2nd buffer; LDS single)
//   S4(i):   64 u16 B-reads (compiler lgkm-tracked vs S3) + 9 MFMAs
// Last-iteration prefetch is masked-safe (p=0, row-0 gathers).
// All LDS mappings/swizzles byte-identical to v9 (validated).
// ============================================================================
__global__ __launch_bounds__(256) void k_agg(
    const unsigned* __restrict__ csru, const int* __restrict__ offs,
    const float* __restrict__ el, const float* __restrict__ er,
    const unsigned* __restrict__ feat, const float* __restrict__ b_gat,
    float* __restrict__ out, int N)
{
    __shared__ __align__(16) char ldsB[32768];   // 4 waves x 8192 B
    const int t = threadIdx.x;
    const int lane = t & 63;
    const int wid = t >> 6;
    const int lc = lane & 15;
    const int hg = lane >> 4;
    char* wlds = ldsB + wid * 8192;

    const int ntiles = (N + 15) >> 4;
    const int tile = blockIdx.x * 4 + wid;
    if (tile >= ntiles) return;
    const int d0 = tile << 4;
    const int dmax = min(16, N - d0);

    const int wstart = offs[d0];
    const int wend = offs[d0 + dmax];
    const int nw = (wend - wstart + 31) >> 5;

    f32x4 accD[8];
    f32x4 accDen = (f32x4)0.f;
#pragma unroll
    for (int nt = 0; nt < 8; nt++) accD[nt] = (f32x4)0.f;

    union { bf16x8 v; unsigned u[4]; } ONESF;
    ONESF.u[0] = ONESF.u[1] = ONESF.u[2] = ONESF.u[3] = 0x3C003C00u;  // fp16 1.0 pair

    // pipeline state
    unsigned ev_n = 0;
    int sj_c = 0, m_c = 0;
    float p_c = 0.f;
    uint4 gv[8];

    // p for window at base w, given its packed ev (exec-masked; er direct load)
    auto computeP = [&](unsigned ev, int wbaseE) -> float {
        float p = 0.f;
        const int eidx = wbaseE + lane;
        if (lane < 32 && eidx < wend) {
            const int sj = (int)(ev & 0xFFFFFu);
            const int m = (int)((ev >> 20) & 15u);
            float ee = el[sj] + er[d0 + m];
            ee = ee >= 0.f ? ee : NEG_SLOPE * ee;
            p = __expf(ee);
        }
        return p;
    };

    if (nw > 0) {
        unsigned ev_c;
        { const int eidx = wstart + lane;
          ev_c = (lane < 32 && eidx < wend) ? csru[eidx] : 0u; }
        if (nw > 1) {
            const int eidx = wstart + 32 + lane;
            ev_n = (lane < 32 && eidx < wend) ? csru[eidx] : 0u;
        }
        sj_c = (int)(ev_c & 0xFFFFFu);
        m_c = (int)((ev_c >> 20) & 15u);
        p_c = computeP(ev_c, wstart);
#pragma unroll
        for (int tt = 0; tt < 8; tt++) {
            const int rsrc = __shfl(sj_c, 4 * tt + hg, 64);
            gv[tt] = *(const uint4*)&feat[(size_t)rsrc * 64 + lc * 4];
        }
    }

    int w = wstart;
    for (int i = 0; i < nw; ++i, w += 32) {
        // ---- S0(i+2): csr prefetch ----
        unsigned ev_f = 0;
        if (i + 2 < nw) {
            const int eidx = w + 64 + lane;
            ev_f = (lane < 32 && eidx < wend) ? csru[eidx] : 0u;
        }

        // ---- S3(i): write gathered window i to LDS (v9 mapping) ----
#pragma unroll
        for (int tt = 0; tt < 8; tt++) {
            const int k = 4 * tt + hg;
            const unsigned woff = ((unsigned)(k * 256 + lc * 16)) ^ (((unsigned)(tt >> 1) & 3u) << 4);
            *(uint4*)(wlds + woff) = gv[tt];
        }

        // ---- A-build(i) from p_c/m_c (uniform flow) ----
        union { bf16x8 v; unsigned u[4]; } A;
#pragma unroll
        for (int jj = 0; jj < 4; jj++) {
            const int sl = 8 * hg + 2 * jj;
            const float p0 = __shfl(p_c, sl, 64);
            const int   m0 = __shfl(m_c, sl, 64);
            const float p1 = __shfl(p_c, sl + 1, 64);
            const int   m1 = __shfl(m_c, sl + 1, 64);
            A.u[jj] = pack_f16((m0 == lc) ? p0 : 0.f, (m1 == lc) ? p1 : 0.f);
        }

        // ---- S1(i+1): next-window p/m/sj ----
        const int sj_n = (int)(ev_n & 0xFFFFFu);
        const int m_n = (int)((ev_n >> 20) & 15u);
        const float p_n = computeP(ev_n, w + 32);

        // ---- S2(i+1): next-window feat gathers into regs ----
#pragma unroll
        for (int tt = 0; tt < 8; tt++) {
            const int rsrc = __shfl(sj_n, 4 * tt + hg, 64);
            gv[tt] = *(const uint4*)&feat[(size_t)rsrc * 64 + lc * 4];
        }

        // ---- S4(i): B reads (v9 mapping) + MFMAs ----
#pragma unroll
        for (int nt = 0; nt < 8; nt++) {
            union { bf16x8 v; unsigned short s[8]; } B;
#pragma unroll
            for (int j = 0; j < 8; j++) {
                const unsigned roff = ((unsigned)((8 * hg + j) * 256 + (nt * 16 + lc) * 2))
                                      ^ (((unsigned)hg & 3u) << 4);
                B.s[j] = *(const unsigned short*)(wlds + roff);
            }
            accD[nt] = __builtin_amdgcn_mfma_f32_16x16x32_f16(A.v, B.v, accD[nt], 0, 0, 0);
        }
        accDen = __builtin_amdgcn_mfma_f32_16x16x32_f16(A.v, ONESF.v, accDen, 0, 0, 0);

        // ---- rotate ----
        ev_n = ev_f;
        sj_c = sj_n; m_c = m_n; p_c = p_n;
    }

    // ---- epilogue: divide by denom, bias, split mu / tanh(logvar) ----
    float inv[4];
#pragma unroll
    for (int r = 0; r < 4; r++) {
        const float den = accDen[r];
        inv[r] = den > 0.f ? 1.f / den : 0.f;
    }

    const size_t nh = (size_t)N * 64;
#pragma unroll
    for (int r = 0; r < 4; r++) {
        const int d = d0 + 4 * hg + r;
        if (d < N) {
#pragma unroll
            for (int nt = 0; nt < 8; nt++) {
                const int c = nt * 16 + lc;
                const float y = accD[nt][r] * inv[r] + b_gat[c];
                if (c < 64) out[(size_t)d * 64 + c] = y;
                else        out[nh + (size_t)d * 64 + (c - 64)] = tanhf(y);
            }
        }
    }
}

extern "C" void kernel_launch(void* const* d_in, const int* in_sizes, int n_in,
                              void* d_out, int out_size, void* d_ws, size_t ws_size,
                              hipStream_t stream) {
    const float* embed  = (const float*)d_in[0];
    const int*   src    = (const int*)d_in[1];
    const int*   dst    = (const int*)d_in[2];
    const float* W_lin  = (const float*)d_in[3];
    const float* b_lin  = (const float*)d_in[4];
    const float* W_gat  = (const float*)d_in[5];
    const float* attn_l = (const float*)d_in[6];
    const float* attn_r = (const float*)d_in[7];
    const float* b_gat  = (const float*)d_in[8];
    float* out = (float*)d_out;

    const int N = in_sizes[0] / 192;
    const int E = in_sizes[1];

    char* ws = (char*)d_ws;
    size_t off = 0;
    auto alloc = [&](size_t bytes) -> void* {
        void* p = ws + off;
        off += (bytes + 255) & ~(size_t)255;
        return p;
    };
    unsigned* feat     = (unsigned*)alloc((size_t)N * 64 * 4);
    float*    el       = (float*)alloc((size_t)N * 4);
    float*    er       = (float*)alloc((size_t)N * 4);
    int*      counts   = (int*)alloc((size_t)N * 4);
    int*      offs     = (int*)alloc(((size_t)N + 1) * 4);
    int*      rank     = (int*)alloc((size_t)E * 4);
    unsigned* csru     = (unsigned*)alloc((size_t)E * 4);
    int*      blocksums= (int*)alloc(1024 * 4);

    hipMemsetAsync(counts, 0, (size_t)N * 4, stream);

    k_gemm<<<(N + 127) / 128, 256, 0, stream>>>(embed, W_lin, b_lin, W_gat,
                                                attn_l, attn_r, feat, el, er, N);
    k_hist<<<(E / 4 + 255) / 256, 256, 0, stream>>>(dst, counts, rank, E);
    const int nb1 = (N + 1023) / 1024;
    k_scan1<<<nb1, 256, 0, stream>>>(counts, offs, blocksums, N);
    k_scan2<<<1, 128, 0, stream>>>(blocksums, nb1);
    k_scan3<<<(N + 255) / 256, 256, 0, stream>>>(offs, blocksums, N, E);
    k_scat<<<(E / 4 + 255) / 256, 256, 0, stream>>>(src, dst, rank, offs, csru, E);

    const int ntiles = (N + 15) / 16;
    k_agg<<<(ntiles + 3) / 4, 256, 0, stream>>>(csru, offs, el, er, feat, b_gat, out, N);
}

// Round 11
// 223.578 us; speedup vs baseline: 1.4077x; 1.4077x over previous
//
#include <hip/hip_runtime.h>
#include <hip/hip_bf16.h>
#include <hip/hip_fp16.h>

#define NEG_SLOPE 0.2f

typedef __attribute__((ext_vector_type(8))) short bf16x8;
typedef __attribute__((ext_vector_type(4))) float f32x4;

__device__ __forceinline__ unsigned pack_bf16(float a, float b) {
    unsigned ua = __float_as_uint(a), ub = __float_as_uint(b);
    ua += 0x7FFFu + ((ua >> 16) & 1u);
    ub += 0x7FFFu + ((ub >> 16) & 1u);
    return (ua >> 16) | (ub & 0xFFFF0000u);
}

__device__ __forceinline__ unsigned pack_f16(float a, float b) {
    union { __half2 h; unsigned u; } cv;
    cv.h = __floats2half2_rn(a, b);
    return cv.u;
}

// ============================================================================
// Fused MFMA kernel: x = relu(embed@W_lin+b_lin); feat = x@W_gat;
// el = feat@attn_l; er = feat@attn_r.
// feat stored STRAIGHT fp16 pairs: feat_u32[n*64+u] = (f16(feat[2u]), f16(feat[2u+1]))
// ============================================================================
__global__ __launch_bounds__(256) void k_gemm(
    const float* __restrict__ embed, const float* __restrict__ W_lin,
    const float* __restrict__ b_lin, const float* __restrict__ W_gat,
    const float* __restrict__ attn_l, const float* __restrict__ attn_r,
    unsigned* __restrict__ feat_u32, float* __restrict__ el,
    float* __restrict__ er, int N)
{
    __shared__ __align__(16) char lds[40960];
    const int t = threadIdx.x;
    const int lane = t & 63;
    const int w = t >> 6;
    const int lc = lane & 15;
    const int hg = lane >> 4;
    const int nb = blockIdx.x * 128;

    // ---- stage W_lin transposed bf16 into LDS [c][k], swizzled ----
    for (int i = t; i < 6144; i += 256) {          // pairs: c in [0,64), kp in [0,96)
        const int c = i & 63, kp = i >> 6;
        const float w0 = W_lin[(2 * kp) * 64 + c];
        const float w1 = W_lin[(2 * kp + 1) * 64 + c];
        const unsigned off = (unsigned)(c * 384 + kp * 4) ^ ((c & 7) << 4);
        *(unsigned*)(lds + off) = pack_bf16(w0, w1);
    }
    // ---- stage W_gat transposed bf16 into LDS [c][k], swizzled ----
    for (int i = t; i < 4096; i += 256) {          // pairs: c in [0,128), kp in [0,32)
        const int c = i & 127, kp = i >> 7;
        const float w0 = W_gat[(2 * kp) * 128 + c];
        const float w1 = W_gat[(2 * kp + 1) * 128 + c];
        const unsigned off = (unsigned)(c * 128 + kp * 4) ^ ((c & 7) << 4);
        *(unsigned*)(lds + 24576 + off) = pack_bf16(w0, w1);
    }
    __syncthreads();

    // ---- GEMM1: x[128][64] = relu(embed[128][192] @ W_lin + b_lin) ----
    f32x4 acc1[2][4];
#pragma unroll
    for (int mt = 0; mt < 2; mt++)
#pragma unroll
        for (int nt = 0; nt < 4; nt++) acc1[mt][nt] = (f32x4)0.f;

#pragma unroll
    for (int ks = 0; ks < 6; ks++) {
        bf16x8 bfr[4];
#pragma unroll
        for (int nt = 0; nt < 4; nt++) {
            const int c = nt * 16 + lc;
            const unsigned off = (unsigned)(c * 384 + ks * 64 + hg * 16) ^ ((c & 7) << 4);
            bfr[nt] = *(const bf16x8*)(lds + off);
        }
#pragma unroll
        for (int mt = 0; mt < 2; mt++) {
            int row = nb + w * 32 + mt * 16 + lc;
            if (row >= N) row = N - 1;
            const float4* ep = (const float4*)(embed + (size_t)row * 192 + ks * 32 + hg * 8);
            const float4 p = ep[0], q = ep[1];
            union { bf16x8 v; unsigned u[4]; } a;
            a.u[0] = pack_bf16(p.x, p.y); a.u[1] = pack_bf16(p.z, p.w);
            a.u[2] = pack_bf16(q.x, q.y); a.u[3] = pack_bf16(q.z, q.w);
#pragma unroll
            for (int nt = 0; nt < 4; nt++)
                acc1[mt][nt] = __builtin_amdgcn_mfma_f32_16x16x32_bf16(a.v, bfr[nt], acc1[mt][nt], 0, 0, 0);
        }
    }

    float blv[4];
#pragma unroll
    for (int nt = 0; nt < 4; nt++) blv[nt] = b_lin[nt * 16 + lc];

    __syncthreads();  // all WT_lin reads done before x overwrites region 0

    // write x (bf16, swizzled) to LDS region 0
#pragma unroll
    for (int mt = 0; mt < 2; mt++)
#pragma unroll
        for (int nt = 0; nt < 4; nt++)
#pragma unroll
            for (int r = 0; r < 4; r++) {
                float v = acc1[mt][nt][r] + blv[nt];
                v = v > 0.f ? v : 0.f;
                const int xrow = w * 32 + mt * 16 + 4 * hg + r;
                const int col = nt * 16 + lc;
                const unsigned off = (unsigned)(xrow * 128 + col * 2) ^ ((xrow & 7) << 4);
                unsigned bv = __float_as_uint(v);
                bv += 0x7FFFu + ((bv >> 16) & 1u);
                *(unsigned short*)(lds + off) = (unsigned short)(bv >> 16);
            }
    __syncthreads();

    // ---- GEMM2: feat[128][128] = x[128][64] @ W_gat ----
    f32x4 acc2[2][8];
#pragma unroll
    for (int mt = 0; mt < 2; mt++)
#pragma unroll
        for (int nt = 0; nt < 8; nt++) acc2[mt][nt] = (f32x4)0.f;

#pragma unroll
    for (int ks = 0; ks < 2; ks++) {
        bf16x8 a2[2];
#pragma unroll
        for (int mt = 0; mt < 2; mt++) {
            const int row = w * 32 + mt * 16 + lc;
            const unsigned off = (unsigned)(row * 128 + ks * 64 + hg * 16) ^ ((row & 7) << 4);
            a2[mt] = *(const bf16x8*)(lds + off);
        }
#pragma unroll
        for (int nt = 0; nt < 8; nt++) {
            const int c = nt * 16 + lc;
            const unsigned off = (unsigned)(c * 128 + ks * 64 + hg * 16) ^ ((c & 7) << 4);
            const bf16x8 b2 = *(const bf16x8*)(lds + 24576 + off);
            acc2[0][nt] = __builtin_amdgcn_mfma_f32_16x16x32_bf16(a2[0], b2, acc2[0][nt], 0, 0, 0);
            acc2[1][nt] = __builtin_amdgcn_mfma_f32_16x16x32_bf16(a2[1], b2, acc2[1][nt], 0, 0, 0);
        }
    }

    // ---- epilogue: el/er + straight-paired feat writes ----
    float alv[8], arv[8];
#pragma unroll
    for (int nt = 0; nt < 8; nt++) {
        alv[nt] = attn_l[nt * 16 + lc];
        arv[nt] = attn_r[nt * 16 + lc];
    }

#pragma unroll
    for (int mt = 0; mt < 2; mt++) {
        const int rbase = nb + w * 32 + mt * 16 + 4 * hg;
        // feat: straight pairs (c, c+1). Lane lc owns col c = nt*16+lc;
        // partner col via shfl_xor(1) (uniform flow); even lanes store u32.
#pragma unroll
        for (int nt = 0; nt < 8; nt++)
#pragma unroll
            for (int r = 0; r < 4; r++) {
                const float V = acc2[mt][nt][r];
                const float Vp = __shfl_xor(V, 1, 64);
                const int row = rbase + r;
                if (!(lc & 1) && row < N)
                    feat_u32[(size_t)row * 64 + nt * 8 + (lc >> 1)] = pack_f16(V, Vp);
            }
        // el/er
        float elv[4] = {0.f, 0.f, 0.f, 0.f}, erv[4] = {0.f, 0.f, 0.f, 0.f};
#pragma unroll
        for (int nt = 0; nt < 8; nt++)
#pragma unroll
            for (int r = 0; r < 4; r++) {
                elv[r] = fmaf(acc2[mt][nt][r], alv[nt], elv[r]);
                erv[r] = fmaf(acc2[mt][nt][r], arv[nt], erv[r]);
            }
#pragma unroll
        for (int r = 0; r < 4; r++) {
#pragma unroll
            for (int o = 1; o < 16; o <<= 1) {
                elv[r] += __shfl_xor(elv[r], o, 64);
                erv[r] += __shfl_xor(erv[r], o, 64);
            }
            const int row = rbase + r;
            if (lc == r && row < N) { el[row] = elv[r]; er[row] = erv[r]; }
        }
    }
}

// histogram + per-edge rank (atomicAdd's return value), ranks stored coalesced
__global__ void k_hist(const int* __restrict__ dst, int* __restrict__ counts,
                       int* __restrict__ rank, int E) {
    const int i = (blockIdx.x * 256 + threadIdx.x) * 4;
    if (i + 3 < E) {
        const int4 v = *(const int4*)&dst[i];
        int4 r;
        r.x = atomicAdd(&counts[v.x], 1);
        r.y = atomicAdd(&counts[v.y], 1);
        r.z = atomicAdd(&counts[v.z], 1);
        r.w = atomicAdd(&counts[v.w], 1);
        *(int4*)&rank[i] = r;
    } else {
        for (int j = i; j < E; j++) rank[j] = atomicAdd(&counts[dst[j]], 1);
    }
}

__global__ __launch_bounds__(256) void k_scan1(
    const int* __restrict__ counts, int* __restrict__ offs,
    int* __restrict__ blocksums, int N)
{
    __shared__ int lds[256];
    const int t = threadIdx.x;
    const int base = blockIdx.x * 1024 + t * 4;
    int c0 = 0, c1 = 0, c2 = 0, c3 = 0;
    if (base + 3 < N) {
        int4 v = *(const int4*)&counts[base];
        c0 = v.x; c1 = v.y; c2 = v.z; c3 = v.w;
    } else {
        if (base + 0 < N) c0 = counts[base + 0];
        if (base + 1 < N) c1 = counts[base + 1];
        if (base + 2 < N) c2 = counts[base + 2];
        if (base + 3 < N) c3 = counts[base + 3];
    }
    const int s = c0 + c1 + c2 + c3;
    lds[t] = s;
    __syncthreads();
    for (int o = 1; o < 256; o <<= 1) {
        int u = (t >= o) ? lds[t - o] : 0;
        __syncthreads();
        lds[t] += u;
        __syncthreads();
    }
    const int excl = lds[t] - s;
    int o0 = excl, o1 = excl + c0, o2 = o1 + c1, o3 = o2 + c2;
    if (base + 3 < N) {
        *(int4*)&offs[base] = make_int4(o0, o1, o2, o3);
    } else {
        if (base + 0 < N) offs[base + 0] = o0;
        if (base + 1 < N) offs[base + 1] = o1;
        if (base + 2 < N) offs[base + 2] = o2;
        if (base + 3 < N) offs[base + 3] = o3;
    }
    if (t == 255) blocksums[blockIdx.x] = lds[255];
}

__global__ void k_scan2(int* __restrict__ blocksums, int nb) {
    __shared__ int lds[128];
    const int t = threadIdx.x;
    const int v = (t < nb) ? blocksums[t] : 0;
    lds[t] = v;
    __syncthreads();
    for (int o = 1; o < 128; o <<= 1) {
        int u = (t >= o) ? lds[t - o] : 0;
        __syncthreads();
        lds[t] += u;
        __syncthreads();
    }
    if (t < nb) blocksums[t] = lds[t] - v;
}

__global__ void k_scan3(int* __restrict__ offs, const int* __restrict__ blocksums,
                        int N, int E) {
    int i = blockIdx.x * 256 + threadIdx.x;
    if (i < N) offs[i] += blocksums[i >> 10];
    if (i == 0) offs[N] = E;  // sentinel
}

// scatter (src | localSeg<<20) into CSR slot: pos = offs[dst] + rank.
// localSeg = dst & 15 (tile-local segment id) -> k_agg needs NO search.
__global__ void k_scat(const int* __restrict__ src, const int* __restrict__ dst,
                       const int* __restrict__ rank, const int* __restrict__ offs,
                       unsigned* __restrict__ csru, int E) {
    const int i = (blockIdx.x * 256 + threadIdx.x) * 4;
    if (i + 3 < E) {
        const int4 s4 = *(const int4*)&src[i];
        const int4 d4 = *(const int4*)&dst[i];
        const int4 r4 = *(const int4*)&rank[i];
        csru[offs[d4.x] + r4.x] = (unsigned)s4.x | ((unsigned)(d4.x & 15) << 20);
        csru[offs[d4.y] + r4.y] = (unsigned)s4.y | ((unsigned)(d4.y & 15) << 20);
        csru[offs[d4.z] + r4.z] = (unsigned)s4.z | ((unsigned)(d4.z & 15) << 20);
        csru[offs[d4.w] + r4.w] = (unsigned)s4.w | ((unsigned)(d4.w & 15) << 20);
    } else {
        for (int j = i; j < E; j++)
            csru[offs[dst[j]] + rank[j]] = (unsigned)src[j] | ((unsigned)(dst[j] & 15) << 20);
    }
}

// ============================================================================
// k_agg v11: v9's proven MFMA-window structure + 2-ahead pipeline, SPILL-PROOF.
// v10's 428MB WRITE_SIZE was the uint4 gv[8] loop-carried array spilling to
// scratch (410MB arithmetic match). Fix: NAMED registers g0..g7, no lambda,
// hand-unrolled gathers/writes, raw el/er loads carried across iterations
// (leaky+exp deferred to A-build), csr prefetch issued last (newest in
// vmcnt queue), __launch_bounds__(256,1) so VGPR budget isn't occupancy-capped.
// All LDS mappings byte-identical to v9 (validated, absmax 1.95e-3).
// ============================================================================
__global__ __launch_bounds__(256, 1) void k_agg(
    const unsigned* __restrict__ csru, const int* __restrict__ offs,
    const float* __restrict__ el, const float* __restrict__ er,
    const unsigned* __restrict__ feat, const float* __restrict__ b_gat,
    float* __restrict__ out, int N)
{
    __shared__ __align__(16) char ldsB[32768];   // 4 waves x 8192 B
    const int t = threadIdx.x;
    const int lane = t & 63;
    const int wid = t >> 6;
    const int lc = lane & 15;
    const int hg = lane >> 4;
    char* wlds = ldsB + wid * 8192;

    const int ntiles = (N + 15) >> 4;
    const int tile = blockIdx.x * 4 + wid;
    if (tile >= ntiles) return;
    const int d0 = tile << 4;
    const int dmax = min(16, N - d0);

    const int wstart = offs[d0];
    const int wend = offs[d0 + dmax];
    const int nw = (wend - wstart + 31) >> 5;

    f32x4 accD[8];
    f32x4 accDen = (f32x4)0.f;
#pragma unroll
    for (int nt = 0; nt < 8; nt++) accD[nt] = (f32x4)0.f;

    union { bf16x8 v; unsigned u[4]; } ONESF;
    ONESF.u[0] = ONESF.u[1] = ONESF.u[2] = ONESF.u[3] = 0x3C003C00u;  // fp16 1.0 pair

    // ---- pipeline state (all named scalars/regs; nothing array-carried) ----
    unsigned ev_n = 0u;
    int m_c = 0;
    float elv_c = -3.4e38f, erv_c = 0.f;
    uint4 g0, g1, g2, g3, g4, g5, g6, g7;
    g0 = g1 = g2 = g3 = g4 = g5 = g6 = g7 = make_uint4(0u, 0u, 0u, 0u);

#define GATHER_ALL(SJ)                                                                      \
    do {                                                                                    \
        int rs_;                                                                            \
        rs_ = __shfl((SJ), 0 + hg, 64);  g0 = *(const uint4*)&feat[(size_t)rs_ * 64 + lc * 4]; \
        rs_ = __shfl((SJ), 4 + hg, 64);  g1 = *(const uint4*)&feat[(size_t)rs_ * 64 + lc * 4]; \
        rs_ = __shfl((SJ), 8 + hg, 64);  g2 = *(const uint4*)&feat[(size_t)rs_ * 64 + lc * 4]; \
        rs_ = __shfl((SJ), 12 + hg, 64); g3 = *(const uint4*)&feat[(size_t)rs_ * 64 + lc * 4]; \
        rs_ = __shfl((SJ), 16 + hg, 64); g4 = *(const uint4*)&feat[(size_t)rs_ * 64 + lc * 4]; \
        rs_ = __shfl((SJ), 20 + hg, 64); g5 = *(const uint4*)&feat[(size_t)rs_ * 64 + lc * 4]; \
        rs_ = __shfl((SJ), 24 + hg, 64); g6 = *(const uint4*)&feat[(size_t)rs_ * 64 + lc * 4]; \
        rs_ = __shfl((SJ), 28 + hg, 64); g7 = *(const uint4*)&feat[(size_t)rs_ * 64 + lc * 4]; \
    } while (0)

    if (nw > 0) {
        const int e0 = wstart + lane;
        const bool v0 = (lane < 32) && (e0 < wend);
        const unsigned ev_c = v0 ? csru[e0] : 0u;
        if (nw > 1) {
            const int e1 = wstart + 32 + lane;
            ev_n = (lane < 32 && e1 < wend) ? csru[e1] : 0u;
        }
        const int sj_c = (int)(ev_c & 0xFFFFFu);
        m_c = (int)((ev_c >> 20) & 15u);
        elv_c = v0 ? el[sj_c] : -3.4e38f;
        erv_c = er[d0 + m_c];
        GATHER_ALL(sj_c);
    }

    int w = wstart;
    for (int i = 0; i < nw; ++i, w += 32) {
        // ---- S3(i): ds_write window i (reads g0..g7 gathered last iter) ----
        // element (k=4tt+hg, chunk lc): byte (k*256 + lc*16) ^ ((k>>3)<<4); k>>3 == tt>>1
        *(uint4*)(wlds + ((unsigned)((0  + hg) * 256 + lc * 16) ^ 0u))  = g0;
        *(uint4*)(wlds + ((unsigned)((4  + hg) * 256 + lc * 16) ^ 0u))  = g1;
        *(uint4*)(wlds + ((unsigned)((8  + hg) * 256 + lc * 16) ^ 16u)) = g2;
        *(uint4*)(wlds + ((unsigned)((12 + hg) * 256 + lc * 16) ^ 16u)) = g3;
        *(uint4*)(wlds + ((unsigned)((16 + hg) * 256 + lc * 16) ^ 32u)) = g4;
        *(uint4*)(wlds + ((unsigned)((20 + hg) * 256 + lc * 16) ^ 32u)) = g5;
        *(uint4*)(wlds + ((unsigned)((24 + hg) * 256 + lc * 16) ^ 48u)) = g6;
        *(uint4*)(wlds + ((unsigned)((28 + hg) * 256 + lc * 16) ^ 48u)) = g7;

        // ---- p(i) from carried raw loads; A-build (uniform flow) ----
        float ee = elv_c + erv_c;
        ee = ee >= 0.f ? ee : NEG_SLOPE * ee;
        const float p_c = __expf(ee);
        union { bf16x8 v; unsigned u[4]; } A;
#pragma unroll
        for (int jj = 0; jj < 4; jj++) {
            const int sl = 8 * hg + 2 * jj;
            const float p0 = __shfl(p_c, sl, 64);
            const int   m0 = __shfl(m_c, sl, 64);
            const float p1 = __shfl(p_c, sl + 1, 64);
            const int   m1 = __shfl(m_c, sl + 1, 64);
            A.u[jj] = pack_f16((m0 == lc) ? p0 : 0.f, (m1 == lc) ? p1 : 0.f);
        }

        // ---- S1(i+1): next-window scalars; raw el/er loads carried ----
        const int sj_n = (int)(ev_n & 0xFFFFFu);
        const int m_n = (int)((ev_n >> 20) & 15u);
        {
            const int e1 = w + 32 + lane;
            const bool vn = (lane < 32) && (e1 < wend);
            elv_c = vn ? el[sj_n] : -3.4e38f;
            erv_c = er[d0 + m_n];
            m_c = m_n;
        }

        // ---- S2(i+1): gathers into named regs (WAR vs ds_write: in-order issue) ----
        GATHER_ALL(sj_n);

        // ---- S0(i+2): csr prefetch issued LAST (newest outstanding) ----
        {
            unsigned ev_f = 0u;
            if (i + 2 < nw) {
                const int e2 = w + 64 + lane;
                ev_f = (lane < 32 && e2 < wend) ? csru[e2] : 0u;
            }
            ev_n = ev_f;
        }

        // ---- S4(i): B reads (v9 mapping) + 9 MFMAs ----
#pragma unroll
        for (int nt = 0; nt < 8; nt++) {
            union { bf16x8 v; unsigned short s[8]; } B;
#pragma unroll
            for (int j = 0; j < 8; j++) {
                const unsigned roff = ((unsigned)((8 * hg + j) * 256 + (nt * 16 + lc) * 2))
                                      ^ (((unsigned)hg & 3u) << 4);
                B.s[j] = *(const unsigned short*)(wlds + roff);
            }
            accD[nt] = __builtin_amdgcn_mfma_f32_16x16x32_f16(A.v, B.v, accD[nt], 0, 0, 0);
        }
        accDen = __builtin_amdgcn_mfma_f32_16x16x32_f16(A.v, ONESF.v, accDen, 0, 0, 0);
    }
#undef GATHER_ALL

    // ---- epilogue: divide by denom, bias, split mu / tanh(logvar) ----
    float inv[4];
#pragma unroll
    for (int r = 0; r < 4; r++) {
        const float den = accDen[r];
        inv[r] = den > 0.f ? 1.f / den : 0.f;
    }

    const size_t nh = (size_t)N * 64;
#pragma unroll
    for (int r = 0; r < 4; r++) {
        const int d = d0 + 4 * hg + r;
        if (d < N) {
#pragma unroll
            for (int nt = 0; nt < 8; nt++) {
                const int c = nt * 16 + lc;
                const float y = accD[nt][r] * inv[r] + b_gat[c];
                if (c < 64) out[(size_t)d * 64 + c] = y;
                else        out[nh + (size_t)d * 64 + (c - 64)] = tanhf(y);
            }
        }
    }
}

extern "C" void kernel_launch(void* const* d_in, const int* in_sizes, int n_in,
                              void* d_out, int out_size, void* d_ws, size_t ws_size,
                              hipStream_t stream) {
    const float* embed  = (const float*)d_in[0];
    const int*   src    = (const int*)d_in[1];
    const int*   dst    = (const int*)d_in[2];
    const float* W_lin  = (const float*)d_in[3];
    const float* b_lin  = (const float*)d_in[4];
    const float* W_gat  = (const float*)d_in[5];
    const float* attn_l = (const float*)d_in[6];
    const float* attn_r = (const float*)d_in[7];
    const float* b_gat  = (const float*)d_in[8];
    float* out = (float*)d_out;

    const int N = in_sizes[0] / 192;
    const int E = in_sizes[1];

    char* ws = (char*)d_ws;
    size_t off = 0;
    auto alloc = [&](size_t bytes) -> void* {
        void* p = ws + off;
        off += (bytes + 255) & ~(size_t)255;
        return p;
    };
    unsigned* feat     = (unsigned*)alloc((size_t)N * 64 * 4);
    float*    el       = (float*)alloc((size_t)N * 4);
    float*    er       = (float*)alloc((size_t)N * 4);
    int*      counts   = (int*)alloc((size_t)N * 4);
    int*      offs     = (int*)alloc(((size_t)N + 1) * 4);
    int*      rank     = (int*)alloc((size_t)E * 4);
    unsigned* csru     = (unsigned*)alloc((size_t)E * 4);
    int*      blocksums= (int*)alloc(1024 * 4);

    hipMemsetAsync(counts, 0, (size_t)N * 4, stream);

    k_gemm<<<(N + 127) / 128, 256, 0, stream>>>(embed, W_lin, b_lin, W_gat,
                                                attn_l, attn_r, feat, el, er, N);
    k_hist<<<(E / 4 + 255) / 256, 256, 0, stream>>>(dst, counts, rank, E);
    const int nb1 = (N + 1023) / 1024;
    k_scan1<<<nb1, 256, 0, stream>>>(counts, offs, blocksums, N);
    k_scan2<<<1, 128, 0, stream>>>(blocksums, nb1);
    k_scan3<<<(N + 255) / 256, 256, 0, stream>>>(offs, blocksums, N, E);
    k_scat<<<(E / 4 + 255) / 256, 256, 0, stream>>>(src, dst, rank, offs, csru, E);

    const int ntiles = (N + 15) / 16;
    k_agg<<<(ntiles + 3) / 4, 256, 0, stream>>>(csru, offs, el, er, feat, b_gat, out, N);
}